// Round 12
// baseline (23.634 us; speedup 1.0000x reference)
//
#include <hip/hip_runtime.h>

#define NCLS 1000
#define NDF  256
#define BB   512
#define WROWS 16
#define WCOLS 64
#define EMAX  24
#define KHALF 128

typedef __attribute__((ext_vector_type(8))) short short8;
typedef __attribute__((ext_vector_type(4))) float floatx4;

static __device__ __forceinline__ unsigned short f2bf(float f) {
    unsigned int u = __float_as_uint(f);
    u += 0x7FFFu + ((u >> 16) & 1u);   // RNE
    return (unsigned short)(u >> 16);
}
static __device__ __forceinline__ short8 cvt8(float4 a, float4 b) {
    short8 r;
    r[0] = (short)f2bf(a.x); r[1] = (short)f2bf(a.y);
    r[2] = (short)f2bf(a.z); r[3] = (short)f2bf(a.w);
    r[4] = (short)f2bf(b.x); r[5] = (short)f2bf(b.y);
    r[6] = (short)f2bf(b.z); r[7] = (short)f2bf(b.w);
    return r;
}

// Single dispatch, no grid sync (R11 math, verified byte-identical), with LDS
// halved via two-K-half B staging and EMAX 24 -> 3-4 blocks/CU instead of 2.
__global__ __launch_bounds__(256, 3) void fused_one(
    const float* __restrict__ df, const int* __restrict__ gt,
    const float* __restrict__ fc, float* __restrict__ out)
{
    __shared__ int                s_gt[BB];
    __shared__ unsigned long long s_mask[WROWS][8];
    __shared__ short              s_slot[BB];
    __shared__ short              s_xrow[EMAX + 8];
    __shared__ int                s_E;
    __shared__ unsigned short     Bh[WCOLS][KHALF + 8];
    __shared__ float              Gown[WROWS][WCOLS + 2];
    __shared__ float              Gx[EMAX][WCOLS + 2];
    __shared__ float              s_v[WROWS];
    __shared__ float              s_vx[EMAX];
    __shared__ float              s_red[WROWS][16];

    int tid = threadIdx.x;
    int j0 = blockIdx.x * WCOLS;
    int m0 = blockIdx.y * WROWS;

    s_gt[tid]         = gt[tid];
    s_gt[tid + 256]   = gt[tid + 256];
    s_slot[tid]       = -1;
    s_slot[tid + 256] = -1;
    if (tid == 0) s_E = 0;
    __syncthreads();                               // B0

    int lane = tid & 63, w = tid >> 6;
    // ballots: occurrence masks for the 16 window classes
    int g0v = s_gt[tid], g1v = s_gt[tid + 256];
#pragma unroll
    for (int r = 0; r < WROWS; ++r) {
        int cls = s_gt[m0 + r];
        unsigned long long b0 = __ballot(g0v == cls);
        unsigned long long b1 = __ballot(g1v == cls);
        if (lane == 0) { s_mask[r][w] = b0; s_mask[r][w + 4] = b1; }
    }
    // own v partials: v[i] = df[i].fc[gt[i]], 16 threads per row
    {
        int rr = tid >> 4, l = tid & 15;
        int irow = m0 + rr, cls = s_gt[irow];
        const float* dp = df + (size_t)irow * NDF + l * 16;
        const float* fp = fc + (size_t)cls * NDF + l * 16;
        float a = 0.f;
#pragma unroll
        for (int u = 0; u < 16; u += 4) {
            float4 x = *(const float4*)(dp + u), y = *(const float4*)(fp + u);
            a += x.x * y.x + x.y * y.y + x.z * y.z + x.w * y.w;
        }
        s_red[rr][l] = a;
    }
    __syncthreads();                               // B1: masks + v-partials

    // extras gather (tid<16; first-in-window classes walk mask bits < m0;
    // distinct classes -> disjoint masks -> race-free). Verified R11.
    if (tid < WROWS) {
        int cls = s_gt[m0 + tid];
        bool first = true;
        for (int r2 = 0; r2 < tid; ++r2)
            if (s_gt[m0 + r2] == cls) { first = false; break; }
        if (first && m0 > 0) {
            for (int wi = 0; wi < 8; ++wi) {
                int base = wi * 64;
                if (base >= m0) break;
                unsigned long long mk = s_mask[tid][wi];
                while (mk) {
                    int b = __builtin_ctzll(mk); mk &= mk - 1ULL;
                    int s = base + b;
                    if (s >= m0) break;
                    int p = atomicAdd(&s_E, 1);
                    if (p < EMAX) { s_slot[s] = (short)p; s_xrow[p] = (short)s; }
                    else          { s_slot[s] = (short)(-2); }
                }
            }
        }
    } else if (tid >= 64 && tid < 64 + WROWS) {    // s_v reduce, other wave
        int rr = tid - 64;
        float v = 0.f;
#pragma unroll
        for (int u = 0; u < 16; ++u) v += s_red[rr][u];
        s_v[rr] = v;
    }
    __syncthreads();                               // B2: E, xrow, s_v final

    int E = s_E; if (E > EMAX) E = EMAX;

    // extras v partials (reuse s_red; E uniform)
    {
        int rr = tid >> 4, l = tid & 15;
        int zi = rr;                               // chunk of 16 extras
        int srow = (zi < E) ? (int)s_xrow[zi] : 0;
        int cls = s_gt[srow];
        const float* dp = df + (size_t)srow * NDF + l * 16;
        const float* fp = fc + (size_t)cls * NDF + l * 16;
        float a = 0.f;
#pragma unroll
        for (int u = 0; u < 16; u += 4) {
            float4 x = *(const float4*)(dp + u), y = *(const float4*)(fp + u);
            a += x.x * y.x + x.y * y.y + x.z * y.z + x.w * y.w;
        }
        s_red[rr][l] = a;
        // second chunk (extras 16..23) handled below via direct 8-row pass
    }
    __syncthreads();                               // B3
    if (tid < EMAX) {
        if (tid < 16) {
            if (tid < E) {
                float v = 0.f;
#pragma unroll
                for (int u = 0; u < 16; ++u) v += s_red[tid][u];
                s_vx[tid] = v;
            }
        } else if (tid < E) {                      // extras 16..23: direct dot
            int srow = (int)s_xrow[tid];
            int cls = s_gt[srow];
            const float* dp = df + (size_t)srow * NDF;
            const float* fp = fc + (size_t)cls * NDF;
            float a = 0.f;
            for (int k = 0; k < NDF; k += 4) {
                float4 x = *(const float4*)(dp + k), y = *(const float4*)(fp + k);
                a += x.x * y.x + x.y * y.y + x.z * y.z + x.w * y.w;
            }
            s_vx[tid] = a;
        }
    }

    // MFMA over two K-halves; acc order ks=0..7 identical to R11.
    int lr = lane & 15, lk8 = (lane >> 4) * 8, cf = w * 16;
    floatx4 accO  = {0.f, 0.f, 0.f, 0.f};
    floatx4 accX0 = accO, accX1 = accO;
    int xr0 = 0, xr1 = 0;
    {   // extras row indices for this lane (read once; valid iff in range)
        if (lr < E)      xr0 = (int)s_xrow[lr];
        if (16 + lr < E) xr1 = (int)s_xrow[16 + lr];
    }
    bool hasX0 = (E > 0), hasX1 = (E > 16);

#pragma unroll
    for (int half = 0; half < 2; ++half) {
        __syncthreads();                           // B4/B6: Bh free for staging
        // stage fc col-tile K-half -> bf16 LDS (OOB cols clamp to 999)
        {
            int row = tid >> 2, kb = (tid & 3) * 32;
            int fr = j0 + row; if (fr > NCLS - 1) fr = NCLS - 1;
            const float* fp = fc + (size_t)fr * NDF + half * KHALF + kb;
#pragma unroll
            for (int u = 0; u < 32; u += 8)
                *(short8*)&Bh[row][kb + u] =
                    cvt8(*(const float4*)(fp + u), *(const float4*)(fp + u + 4));
        }
        __syncthreads();                           // B5/B7: Bh ready

        const float* apO = df + (size_t)(m0 + lr) * NDF + half * KHALF + lk8;
        const float* ap0 = df + (size_t)xr0 * NDF + half * KHALF + lk8;
        const float* ap1 = df + (size_t)xr1 * NDF + half * KHALF + lk8;
#pragma unroll
        for (int ks = 0; ks < 4; ++ks) {
            int kb = ks * 32;
            short8 bfrag = *(short8*)&Bh[cf + lr][kb + lk8];
            short8 a = cvt8(*(const float4*)(apO + kb), *(const float4*)(apO + kb + 4));
            accO = __builtin_amdgcn_mfma_f32_16x16x32_bf16(a, bfrag, accO, 0, 0, 0);
            if (hasX0) {
                short8 a0 = cvt8(*(const float4*)(ap0 + kb), *(const float4*)(ap0 + kb + 4));
                accX0 = __builtin_amdgcn_mfma_f32_16x16x32_bf16(a0, bfrag, accX0, 0, 0, 0);
            }
            if (hasX1) {
                short8 a1 = cvt8(*(const float4*)(ap1 + kb), *(const float4*)(ap1 + kb + 4));
                accX1 = __builtin_amdgcn_mfma_f32_16x16x32_bf16(a1, bfrag, accX1, 0, 0, 0);
            }
        }
    }
    // C/D layout: col = lane&15, row = (lane>>4)*4 + g  [m89-verified]
    {
        int rb = (lane >> 4) * 4;
#pragma unroll
        for (int g = 0; g < 4; ++g) Gown[rb + g][cf + lr] = accO[g];
        if (hasX0) {
#pragma unroll
            for (int g = 0; g < 4; ++g)
                if (rb + g < E) Gx[rb + g][cf + lr] = accX0[g];
        }
        if (hasX1) {
#pragma unroll
            for (int g = 0; g < 4; ++g)
                if (16 + rb + g < E) Gx[16 + rb + g][cf + lr] = accX1[g];
        }
    }
    __syncthreads();                               // B8: Gown/Gx/s_vx ready

    // walk: thread (r,c) -> row m0+r, cols j0+c*4..+3; ascending set bits;
    // final mcnt == n, so 1/n applies as a postfactor. (R11-verified)
    int r = tid >> 4, c = tid & 15;
    int i_row = m0 + r;
    int jc = j0 + c * 4;
    int mcnt = 0;
    float St = 0.f;
    float S0 = 0.f, S1 = 0.f, S2 = 0.f, S3 = 0.f;
    float q0 = 0.f, q1 = 0.f, q2 = 0.f, q3 = 0.f;
    for (int wi = 0; wi < 8; ++wi) {
        int base = wi * 64;
        if (base > i_row) break;
        unsigned long long mk = s_mask[r][wi];
        while (mk) {
            int b = __builtin_ctzll(mk); mk &= mk - 1ULL;
            int s = base + b;
            if (s > i_row) break;
            float vz, G0, G1, G2, G3;
            if (s >= m0) {
                int rr = s - m0;
                vz = s_v[rr];
                G0 = Gown[rr][c * 4 + 0]; G1 = Gown[rr][c * 4 + 1];
                G2 = Gown[rr][c * 4 + 2]; G3 = Gown[rr][c * 4 + 3];
            } else {
                int slot = (int)s_slot[s];
                if (slot >= 0) {
                    vz = s_vx[slot];
                    G0 = Gx[slot][c * 4 + 0]; G1 = Gx[slot][c * 4 + 1];
                    G2 = Gx[slot][c * 4 + 2]; G3 = Gx[slot][c * 4 + 3];
                } else {
                    // overflow fallback (E > EMAX; effectively never taken)
                    const float* dp = df + (size_t)s * NDF;
                    const float* fv = fc + (size_t)s_gt[s] * NDF;
                    int p0 = jc     < NCLS ? jc     : NCLS - 1;
                    int p1 = jc + 1 < NCLS ? jc + 1 : NCLS - 1;
                    int p2 = jc + 2 < NCLS ? jc + 2 : NCLS - 1;
                    int p3 = jc + 3 < NCLS ? jc + 3 : NCLS - 1;
                    vz = 0.f; G0 = G1 = G2 = G3 = 0.f;
                    for (int k = 0; k < NDF; ++k) {
                        float d = dp[k];
                        vz += d * fv[k];
                        G0 += d * fc[(size_t)p0 * NDF + k];
                        G1 += d * fc[(size_t)p1 * NDF + k];
                        G2 += d * fc[(size_t)p2 * NDF + k];
                        G3 += d * fc[(size_t)p3 * NDF + k];
                    }
                }
            }
            ++mcnt;
            St += vz;
            float inv_m = 1.f / (float)mcnt;
            S0 += G0; S1 += G1; S2 += G2; S3 += G3;
            if (mcnt >= 2) {
                float ht = vz - St * inv_m;
                float coef = (float)(mcnt - 1) * inv_m;
                float h0 = (G0 - S0 * inv_m) - ht;
                float h1 = (G1 - S1 * inv_m) - ht;
                float h2 = (G2 - S2 * inv_m) - ht;
                float h3 = (G3 - S3 * inv_m) - ht;
                q0 += coef * h0 * h0;
                q1 += coef * h1 * h1;
                q2 += coef * h2 * h2;
                q3 += coef * h3 * h3;
            }
        }
    }
    if (jc < NCLS) {                               // NCLS%4==0 -> exact guard
        float invn = 1.f / (float)mcnt;
        float sc = 0.05f * invn;                   // 0.5*ALP / n
        float vi = s_v[r];
        *(float4*)&out[(size_t)i_row * NCLS + jc] = make_float4(
            (Gown[r][c * 4 + 0] - vi) + sc * q0,
            (Gown[r][c * 4 + 1] - vi) + sc * q1,
            (Gown[r][c * 4 + 2] - vi) + sc * q2,
            (Gown[r][c * 4 + 3] - vi) + sc * q3);
    }
}

extern "C" void kernel_launch(void* const* d_in, const int* in_sizes, int n_in,
                              void* d_out, int out_size, void* d_ws, size_t ws_size,
                              hipStream_t stream) {
    const float* df = (const float*)d_in[0];
    const int*   gt = (const int*)d_in[1];
    const float* fc = (const float*)d_in[2];
    float* out = (float*)d_out;
    (void)d_ws; (void)ws_size;

    fused_one<<<dim3(16, 32), 256, 0, stream>>>(df, gt, fc, out);
}

// Round 13
// 14.715 us; speedup vs baseline: 1.6060x; 1.6060x over previous
//
#include <hip/hip_runtime.h>

#define NCLS 1000
#define NDF  256
#define BB   512
#define O_LD 1024

#define BM 32
#define BN 64
#define BK 32
#define NCHUNK (NDF / BK)   // 8

typedef __attribute__((ext_vector_type(8))) short short8;
typedef __attribute__((ext_vector_type(4))) float floatx4;

static __device__ __forceinline__ unsigned short f2bf(float f) {
    unsigned int u = __float_as_uint(f);
    u += 0x7FFFu + ((u >> 16) & 1u);   // RNE
    return (unsigned short)(u >> 16);
}

// ---------------- K1: G = df . fc^T via bf16 MFMA (verified R5) ----------------
template <bool FULL>
static __device__ __forceinline__ void run_pipe(
    const float* __restrict__ ap, const float* __restrict__ bp, bool bok,
    unsigned short (&Ah)[2][BM][BK], unsigned short (&Bh)[2][BN][BK],
    int arow, int ak, int brow, int bk,
    int r16, int c32, int lr, int lk,
    floatx4& acc0, floatx4& acc1)
{
    float4 va = *(const float4*)ap;
    float4 vb0, vb1;
    if (FULL || bok) { vb0 = *(const float4*)bp; vb1 = *(const float4*)(bp + 4); }
    else { vb0 = make_float4(0.f, 0.f, 0.f, 0.f); vb1 = vb0; }

    *(ushort4*)&Ah[0][arow][ak] =
        make_ushort4(f2bf(va.x), f2bf(va.y), f2bf(va.z), f2bf(va.w));
    *(ushort4*)&Bh[0][brow][bk] =
        make_ushort4(f2bf(vb0.x), f2bf(vb0.y), f2bf(vb0.z), f2bf(vb0.w));
    *(ushort4*)&Bh[0][brow][bk + 4] =
        make_ushort4(f2bf(vb1.x), f2bf(vb1.y), f2bf(vb1.z), f2bf(vb1.w));
    __syncthreads();

    for (int c = 0; c < NCHUNK; ++c) {
        int cur = c & 1;
        float4 na, nb0, nb1;
        if (c + 1 < NCHUNK) {
            int k0 = (c + 1) * BK;
            na = *(const float4*)(ap + k0);
            if (FULL || bok) {
                nb0 = *(const float4*)(bp + k0);
                nb1 = *(const float4*)(bp + k0 + 4);
            } else {
                nb0 = make_float4(0.f, 0.f, 0.f, 0.f); nb1 = nb0;
            }
        }
        short8 a  = *(const short8*)&Ah[cur][r16 + lr][lk];
        short8 b0 = *(const short8*)&Bh[cur][c32 + lr][lk];
        short8 b1 = *(const short8*)&Bh[cur][c32 + 16 + lr][lk];
        acc0 = __builtin_amdgcn_mfma_f32_16x16x32_bf16(a, b0, acc0, 0, 0, 0);
        acc1 = __builtin_amdgcn_mfma_f32_16x16x32_bf16(a, b1, acc1, 0, 0, 0);
        if (c + 1 < NCHUNK) {
            int nxt = cur ^ 1;
            *(ushort4*)&Ah[nxt][arow][ak] =
                make_ushort4(f2bf(na.x), f2bf(na.y), f2bf(na.z), f2bf(na.w));
            *(ushort4*)&Bh[nxt][brow][bk] =
                make_ushort4(f2bf(nb0.x), f2bf(nb0.y), f2bf(nb0.z), f2bf(nb0.w));
            *(ushort4*)&Bh[nxt][brow][bk + 4] =
                make_ushort4(f2bf(nb1.x), f2bf(nb1.y), f2bf(nb1.z), f2bf(nb1.w));
            __syncthreads();
        }
    }
}

__global__ __launch_bounds__(256) void gemm_mfma(const float* __restrict__ df,
                                                 const float* __restrict__ fc,
                                                 float* __restrict__ O) {
    __shared__ unsigned short Ah[2][BM][BK];
    __shared__ unsigned short Bh[2][BN][BK];
    int tid = threadIdx.x;
    int m0 = blockIdx.y * BM;
    int j0 = blockIdx.x * BN;

    int arow = tid >> 3, ak = (tid & 7) * 4;
    int brow = tid >> 2, bk = (tid & 3) * 8;
    const float* ap = df + (size_t)(m0 + arow) * NDF + ak;
    const float* bp = fc + (size_t)(j0 + brow) * NDF + bk;
    bool bok = (j0 + brow) < NCLS;

    int lane = tid & 63, w = tid >> 6;
    int r16 = (w & 1) * 16, c32 = (w >> 1) * 32;
    int lr = lane & 15, lk = (lane >> 4) * 8;

    floatx4 acc0 = {0.f, 0.f, 0.f, 0.f}, acc1 = {0.f, 0.f, 0.f, 0.f};

    if (j0 + BN <= NCLS) {
        run_pipe<true>(ap, bp, bok, Ah, Bh, arow, ak, brow, bk,
                       r16, c32, lr, lk, acc0, acc1);
    } else {
        run_pipe<false>(ap, bp, bok, Ah, Bh, arow, ak, brow, bk,
                        r16, c32, lr, lk, acc0, acc1);
    }

    // C/D layout: col = lane&15, row = (lane>>4)*4 + reg   [m89-verified]
    int orow = m0 + r16 + (lane >> 4) * 4;
    int ocol = j0 + c32 + lr;
#pragma unroll
    for (int r = 0; r < 4; ++r) {
        O[(size_t)(orow + r) * O_LD + ocol]      = acc0[r];
        O[(size_t)(orow + r) * O_LD + ocol + 16] = acc1[r];
    }
}

// ---------------- K2: combine with in-block ballot occurrence scan ----------------
// One block per row i (512 threads). Wave ballots of (gt[k]==gt[i]) give 8x64-bit
// occurrence masks; n = popcount of bits <= i; walk set bits ascending -- same
// arithmetic sequence as the R5 occStep walk. Scalar per-thread state only.
__global__ __launch_bounds__(512) void combine_fused(
    const int* __restrict__ gt, const float* __restrict__ O,
    float* __restrict__ out)
{
    __shared__ unsigned long long masks[8];
    int tid = threadIdx.x;
    int i = blockIdx.x;
    int t = gt[i];                       // broadcast
    int g = gt[tid];                     // coalesced
    unsigned long long bal = __ballot(g == t);
    if ((tid & 63) == 0) masks[tid >> 6] = bal;
    __syncthreads();

    int j = tid * 2;
    if (j >= NCLS) return;               // after the barrier; no barriers below

    // n = #occurrences of class t at positions <= i (always >= 1)
    int n = 0;
#pragma unroll
    for (int wi = 0; wi < 8; ++wi) {
        int d = i - wi * 64;
        unsigned long long mk = masks[wi];
        if (d >= 64)      n += __popcll(mk);
        else if (d >= 0)  n += __popcll(mk & ((2ULL << d) - 1ULL));  // d=63 -> all ones
    }

    const float* Grow = O + (size_t)i * O_LD;
    float2 gv = *(const float2*)&Grow[j];
    float gtv = Grow[t];
    float gx = gv.x - gtv, gy = gv.y - gtv;
    float qx = 0.f, qy = 0.f;

    if (n >= 2) {
        float invn = 1.f / (float)n;
        float Sx = 0.f, Sy = 0.f, St = 0.f;
        int m = 0;
        for (int wi = 0; wi < 8 && m < n; ++wi) {
            unsigned long long mk = masks[wi];
            while (mk && m < n) {
                int b = __builtin_ctzll(mk);
                mk &= mk - 1ULL;
                int s = wi * 64 + b;
                float2 Gsj = *(const float2*)&O[(size_t)s * O_LD + j];
                float Gst = O[(size_t)s * O_LD + t];
                ++m;
                Sx += Gsj.x; Sy += Gsj.y; St += Gst;
                if (m >= 2) {
                    float inv_m = 1.f / (float)m;
                    float ht = Gst - St * inv_m;
                    float hx = (Gsj.x - Sx * inv_m) - ht;
                    float hy = (Gsj.y - Sy * inv_m) - ht;
                    float coef = (float)(m - 1) * inv_m * invn;
                    qx += coef * hx * hx;
                    qy += coef * hy * hy;
                }
            }
        }
    }
    // j even, NCLS even -> float2 store always in-bounds when j < NCLS
    *(float2*)&out[(size_t)i * NCLS + j] =
        make_float2(gx + 0.05f * qx, gy + 0.05f * qy);   // 0.5*ALP = 0.05
}

extern "C" void kernel_launch(void* const* d_in, const int* in_sizes, int n_in,
                              void* d_out, int out_size, void* d_ws, size_t ws_size,
                              hipStream_t stream) {
    const float* df = (const float*)d_in[0];
    const int*   gt = (const int*)d_in[1];
    const float* fc = (const float*)d_in[2];
    float* out = (float*)d_out;

    float* O = (float*)d_ws;   // 512*1024*4 = 2 MB of workspace

    gemm_mfma<<<dim3(16, 16), 256, 0, stream>>>(df, fc, O);
    combine_fused<<<BB, 512, 0, stream>>>(gt, O, out);
}